// Round 1
// baseline (242.151 us; speedup 1.0000x reference)
//
#include <hip/hip_runtime.h>
#include <math.h>
#include <stdint.h>

// SPD encoder: out[b] = vech_triu( logm( M^T X[b] M ) ), M = W1 W2 W3 (9x3).
// All ReEig clamps are provably no-ops (lambda_min >= 1e-3 > EPS=1e-4), so the
// 7x7/5x5 eigensolves vanish; only one 3x3 symmetric eig (Jacobi) per matrix.
//
// One wave (64 threads) per 64 consecutive matrices:
//   - coalesced float4 global->LDS staging (wave span = 20736 B, 16B aligned)
//   - per-lane LDS reads, stride 81 dwords -> 2-way bank aliasing (free)
//   - per-lane 3x3 Jacobi (6 sweeps, fully unrolled, all-static indexing)

#define JACOBI_ROT(app, aqq, apq, arp, arq, vp0, vq0, vp1, vq1, vp2, vq2)      \
  do {                                                                         \
    float _apq = apq;                                                          \
    if (fabsf(_apq) > 1e-30f) {                                                \
      float _app = app, _aqq = aqq;                                            \
      float _tau = (_aqq - _app) / (2.f * _apq);                               \
      float _t = copysignf(1.f, _tau) /                                        \
                 (fabsf(_tau) + sqrtf(fmaf(_tau, _tau, 1.f)));                 \
      float _c = 1.f / sqrtf(fmaf(_t, _t, 1.f));                               \
      float _s = _t * _c;                                                      \
      float _arp = arp, _arq = arq;                                            \
      arp = _c * _arp - _s * _arq;                                             \
      arq = _s * _arp + _c * _arq;                                             \
      app = fmaf(-_t, _apq, _app);                                             \
      aqq = fmaf(_t, _apq, _aqq);                                              \
      apq = 0.f;                                                               \
      float _v;                                                                \
      _v = vp0; vp0 = _c * _v - _s * vq0; vq0 = _s * _v + _c * vq0;            \
      _v = vp1; vp1 = _c * _v - _s * vq1; vq1 = _s * _v + _c * vq1;            \
      _v = vp2; vp2 = _c * _v - _s * vq2; vq2 = _s * _v + _c * vq2;            \
    }                                                                          \
  } while (0)

__global__ __launch_bounds__(64) void spd_encoder_kernel(
    const float* __restrict__ X,
    const float* __restrict__ W1,
    const float* __restrict__ W2,
    const float* __restrict__ W3,
    float* __restrict__ out)
{
    __shared__ float sX[5184];   // 64 matrices * 81 floats = 20736 B
    __shared__ float sM[27];     // M = W1@W2@W3, 9x3 row-major

    const int lane = threadIdx.x;                      // 0..63
    const long long base = (long long)blockIdx.x * 64; // first matrix index

    // ---- M = W1(9x7) @ W2(7x5) @ W3(5x3), threads 0..26, one entry each ----
    if (lane < 27) {
        const int i = lane / 3, c = lane % 3;
        float acc = 0.f;
        #pragma unroll
        for (int a = 0; a < 7; ++a) {
            float p = 0.f;
            #pragma unroll
            for (int b = 0; b < 5; ++b)
                p = fmaf(W2[a * 5 + b], W3[b * 3 + c], p);
            acc = fmaf(W1[i * 7 + a], p, acc);
        }
        sM[lane] = acc;
    }

    // ---- stage 64 matrices into LDS, fully coalesced float4 loads ----
    {
        const float4* __restrict__ g4 = (const float4*)(X + base * 81); // blk*20736 B, 16B aligned
        float4* l4 = (float4*)sX;
        #pragma unroll
        for (int k = 0; k < 20; ++k)
            l4[k * 64 + lane] = g4[k * 64 + lane];     // floats [0, 5120)
        sX[5120 + lane] = X[base * 81 + 5120 + lane];  // remainder 64 floats
    }

    __syncthreads();

    // ---- per-lane M in registers (27 VGPRs) ----
    float M[9][3];
    #pragma unroll
    for (int i = 0; i < 9; ++i)
        #pragma unroll
        for (int c = 0; c < 3; ++c)
            M[i][c] = sM[i * 3 + c];

    // ---- T = X * M (9x3); LDS reads: bank = (81*lane + e) % 32, 2-way only ----
    const float* __restrict__ x = sX + lane * 81;
    float T[9][3];
    #pragma unroll
    for (int i = 0; i < 9; ++i) {
        float t0 = 0.f, t1 = 0.f, t2 = 0.f;
        #pragma unroll
        for (int j = 0; j < 9; ++j) {
            const float xv = x[i * 9 + j];
            t0 = fmaf(xv, M[j][0], t0);
            t1 = fmaf(xv, M[j][1], t1);
            t2 = fmaf(xv, M[j][2], t2);
        }
        T[i][0] = t0; T[i][1] = t1; T[i][2] = t2;
    }

    // ---- Y = M^T * T, symmetric 3x3 (6 entries) ----
    float A00 = 0.f, A01 = 0.f, A02 = 0.f, A11 = 0.f, A12 = 0.f, A22 = 0.f;
    #pragma unroll
    for (int i = 0; i < 9; ++i) {
        A00 = fmaf(M[i][0], T[i][0], A00);
        A01 = fmaf(M[i][0], T[i][1], A01);
        A02 = fmaf(M[i][0], T[i][2], A02);
        A11 = fmaf(M[i][1], T[i][1], A11);
        A12 = fmaf(M[i][1], T[i][2], A12);
        A22 = fmaf(M[i][2], T[i][2], A22);
    }

    // ---- Jacobi eig of 3x3 symmetric; V accumulates eigenvectors (columns) ----
    float V00 = 1.f, V01 = 0.f, V02 = 0.f;
    float V10 = 0.f, V11 = 1.f, V12 = 0.f;
    float V20 = 0.f, V21 = 0.f, V22 = 1.f;

    #pragma unroll
    for (int sw = 0; sw < 6; ++sw) {
        // (p,q,r) = (0,1,2)
        JACOBI_ROT(A00, A11, A01, A02, A12, V00, V01, V10, V11, V20, V21);
        // (p,q,r) = (0,2,1)
        JACOBI_ROT(A00, A22, A02, A01, A12, V00, V02, V10, V12, V20, V22);
        // (p,q,r) = (1,2,0)
        JACOBI_ROT(A11, A22, A12, A01, A02, V01, V02, V11, V12, V21, V22);
    }

    // ---- logm reconstruction: L = V diag(log w) V^T ----
    const float lw0 = logf(fmaxf(A00, 1e-12f));
    const float lw1 = logf(fmaxf(A11, 1e-12f));
    const float lw2 = logf(fmaxf(A22, 1e-12f));

    const float L00 = lw0 * V00 * V00 + lw1 * V01 * V01 + lw2 * V02 * V02;
    const float L01 = lw0 * V00 * V10 + lw1 * V01 * V11 + lw2 * V02 * V12;
    const float L02 = lw0 * V00 * V20 + lw1 * V01 * V21 + lw2 * V02 * V22;
    const float L11 = lw0 * V10 * V10 + lw1 * V11 * V11 + lw2 * V12 * V12;
    const float L12 = lw0 * V10 * V20 + lw1 * V11 * V21 + lw2 * V12 * V22;
    const float L22 = lw0 * V20 * V20 + lw1 * V21 * V21 + lw2 * V22 * V22;

    // ---- vech upper triangle: (0,0),(0,1),(0,2),(1,1),(1,2),(2,2) ----
    float2* o2 = (float2*)(out + (base + lane) * 6);   // 24B stride, 8B aligned
    o2[0] = make_float2(L00, L01);
    o2[1] = make_float2(L02, L11);
    o2[2] = make_float2(L12, L22);
}

extern "C" void kernel_launch(void* const* d_in, const int* in_sizes, int n_in,
                              void* d_out, int out_size, void* d_ws, size_t ws_size,
                              hipStream_t stream) {
    const float* X  = (const float*)d_in[0];
    const float* W1 = (const float*)d_in[1];
    const float* W2 = (const float*)d_in[2];
    const float* W3 = (const float*)d_in[3];
    float* out = (float*)d_out;

    const int B = in_sizes[0] / 81;        // 524288
    const int nblocks = B / 64;            // 8192 one-wave blocks
    spd_encoder_kernel<<<nblocks, 64, 0, stream>>>(X, W1, W2, W3, out);
}

// Round 2
// 239.145 us; speedup vs baseline: 1.0126x; 1.0126x over previous
//
#include <hip/hip_runtime.h>
#include <math.h>
#include <stdint.h>

// SPD encoder: out[b] = vech_triu( logm( M^T X[b] M ) ), M = W1 W2 W3 (9x3).
// ReEig clamps are provably no-ops (lambda_min >= 1e-3 > EPS=1e-4), so the
// 7x7/5x5 eigensolves vanish; only one 3x3 symmetric eig (Jacobi) per matrix.
//
// R2 changes vs R1 (latency-bound at 7 waves/CU, 1.75/SIMD):
//  - global->LDS staging via __builtin_amdgcn_global_load_lds width=16
//    (no VGPR round-trip, no address VALU, fetch starts at instr 0;
//    LDS dest is wave-uniform base + lane*16 -> identity layout, matches)
//  - fast-math Jacobi: v_rcp/v_rsq/v_sqrt raw intrinsics + branchless guard
//    (kills the IEEE div/sqrt expansions that made an ~1800-cycle dep chain)
//  - 5 sweeps (15 rotations) instead of 6; __log via v_log_f32 * ln2

#define GLOBAL_AS __attribute__((address_space(1)))
#define LDS_AS    __attribute__((address_space(3)))

__device__ __forceinline__ float fast_rcp(float x)  { return __builtin_amdgcn_rcpf(x); }
__device__ __forceinline__ float fast_rsq(float x)  { return __builtin_amdgcn_rsqf(x); }
__device__ __forceinline__ float fast_sqrt(float x) { return __builtin_amdgcn_sqrtf(x); }
__device__ __forceinline__ float fast_log(float x)  { return __builtin_amdgcn_logf(x) * 0.69314718056f; }

// One Jacobi rotation on (p,q), r = third index. Branchless: when |apq| is
// tiny, t is forced to 0 via cndmask (c=1, s=0 -> identity rotation).
#define JACOBI_ROT(app, aqq, apq, arp, arq, vp0, vq0, vp1, vq1, vp2, vq2)      \
  do {                                                                         \
    float _apq = apq;                                                          \
    float _tau = (aqq - app) * 0.5f * fast_rcp(_apq);                          \
    float _t = copysignf(fast_rcp(fabsf(_tau) + fast_sqrt(fmaf(_tau, _tau, 1.f))), _tau); \
    _t = (fabsf(_apq) > 1e-20f) ? _t : 0.f;                                    \
    float _c = fast_rsq(fmaf(_t, _t, 1.f));                                    \
    float _s = _t * _c;                                                        \
    float _arp = arp, _arq = arq;                                              \
    arp = _c * _arp - _s * _arq;                                               \
    arq = _s * _arp + _c * _arq;                                               \
    app = fmaf(-_t, _apq, app);                                                \
    aqq = fmaf(_t, _apq, aqq);                                                 \
    apq = 0.f;                                                                 \
    float _v;                                                                  \
    _v = vp0; vp0 = _c * _v - _s * vq0; vq0 = _s * _v + _c * vq0;              \
    _v = vp1; vp1 = _c * _v - _s * vq1; vq1 = _s * _v + _c * vq1;              \
    _v = vp2; vp2 = _c * _v - _s * vq2; vq2 = _s * _v + _c * vq2;              \
  } while (0)

__global__ __launch_bounds__(64) void spd_encoder_kernel(
    const float* __restrict__ X,
    const float* __restrict__ W1,
    const float* __restrict__ W2,
    const float* __restrict__ W3,
    float* __restrict__ out)
{
    __shared__ float sX[5184];   // 64 matrices * 81 floats = 20736 B (identity layout)
    __shared__ float sM[27];     // M = W1@W2@W3, 9x3 row-major

    const int lane = threadIdx.x;                      // 0..63
    const long long base = (long long)blockIdx.x * 64; // first matrix index

    // ---- async global->LDS staging, issued first so HBM fetch starts now ----
    // chunk k: bytes [k*1024, k*1024+1024) -> LDS same offsets (lane*16 implicit)
    {
        GLOBAL_AS const float* g = (GLOBAL_AS const float*)(X + base * 81);
        #pragma unroll
        for (int k = 0; k < 20; ++k)
            __builtin_amdgcn_global_load_lds(
                (GLOBAL_AS const void*)(g + k * 256 + lane * 4),
                (LDS_AS void*)(sX + k * 256), 16, 0, 0);
        // tail 256 B: floats [5120, 5184), width 4 (lane*4 implicit)
        __builtin_amdgcn_global_load_lds(
            (GLOBAL_AS const void*)(g + 5120 + lane),
            (LDS_AS void*)(sX + 5120), 4, 0, 0);
    }

    // ---- M = W1(9x7) @ W2(7x5) @ W3(5x3), lanes 0..26, overlapped w/ fetch ----
    if (lane < 27) {
        const int i = lane / 3, c = lane % 3;
        float acc = 0.f;
        #pragma unroll
        for (int a = 0; a < 7; ++a) {
            float p = 0.f;
            #pragma unroll
            for (int b = 0; b < 5; ++b)
                p = fmaf(W2[a * 5 + b], W3[b * 3 + c], p);
            acc = fmaf(W1[i * 7 + a], p, acc);
        }
        sM[lane] = acc;
    }

    __syncthreads();   // drains vmcnt (global_load_lds) + lgkm (sM writes)

    // ---- per-lane M in registers ----
    float M[9][3];
    #pragma unroll
    for (int i = 0; i < 9; ++i)
        #pragma unroll
        for (int c = 0; c < 3; ++c)
            M[i][c] = sM[i * 3 + c];

    // ---- T = X * M (9x3); lane stride 81 dwords -> 2-way bank alias (free) ----
    const float* __restrict__ x = sX + lane * 81;
    float T[9][3];
    #pragma unroll
    for (int i = 0; i < 9; ++i) {
        float t0 = 0.f, t1 = 0.f, t2 = 0.f;
        #pragma unroll
        for (int j = 0; j < 9; ++j) {
            const float xv = x[i * 9 + j];
            t0 = fmaf(xv, M[j][0], t0);
            t1 = fmaf(xv, M[j][1], t1);
            t2 = fmaf(xv, M[j][2], t2);
        }
        T[i][0] = t0; T[i][1] = t1; T[i][2] = t2;
    }

    // ---- Y = M^T * T, symmetric 3x3 (6 entries) ----
    float A00 = 0.f, A01 = 0.f, A02 = 0.f, A11 = 0.f, A12 = 0.f, A22 = 0.f;
    #pragma unroll
    for (int i = 0; i < 9; ++i) {
        A00 = fmaf(M[i][0], T[i][0], A00);
        A01 = fmaf(M[i][0], T[i][1], A01);
        A02 = fmaf(M[i][0], T[i][2], A02);
        A11 = fmaf(M[i][1], T[i][1], A11);
        A12 = fmaf(M[i][1], T[i][2], A12);
        A22 = fmaf(M[i][2], T[i][2], A22);
    }

    // ---- Jacobi eig (5 cyclic sweeps, fully unrolled) ----
    float V00 = 1.f, V01 = 0.f, V02 = 0.f;
    float V10 = 0.f, V11 = 1.f, V12 = 0.f;
    float V20 = 0.f, V21 = 0.f, V22 = 1.f;

    #pragma unroll
    for (int sw = 0; sw < 5; ++sw) {
        JACOBI_ROT(A00, A11, A01, A02, A12, V00, V01, V10, V11, V20, V21); // (0,1)
        JACOBI_ROT(A00, A22, A02, A01, A12, V00, V02, V10, V12, V20, V22); // (0,2)
        JACOBI_ROT(A11, A22, A12, A01, A02, V01, V02, V11, V12, V21, V22); // (1,2)
    }

    // ---- logm reconstruction: L = V diag(log w) V^T ----
    const float lw0 = fast_log(fmaxf(A00, 1e-12f));
    const float lw1 = fast_log(fmaxf(A11, 1e-12f));
    const float lw2 = fast_log(fmaxf(A22, 1e-12f));

    const float L00 = lw0 * V00 * V00 + lw1 * V01 * V01 + lw2 * V02 * V02;
    const float L01 = lw0 * V00 * V10 + lw1 * V01 * V11 + lw2 * V02 * V12;
    const float L02 = lw0 * V00 * V20 + lw1 * V01 * V21 + lw2 * V02 * V22;
    const float L11 = lw0 * V10 * V10 + lw1 * V11 * V11 + lw2 * V12 * V12;
    const float L12 = lw0 * V10 * V20 + lw1 * V11 * V21 + lw2 * V12 * V22;
    const float L22 = lw0 * V20 * V20 + lw1 * V21 * V21 + lw2 * V22 * V22;

    // ---- vech upper triangle: (0,0),(0,1),(0,2),(1,1),(1,2),(2,2) ----
    float2* o2 = (float2*)(out + (base + lane) * 6);   // 24B stride, 8B aligned
    o2[0] = make_float2(L00, L01);
    o2[1] = make_float2(L02, L11);
    o2[2] = make_float2(L12, L22);
}

extern "C" void kernel_launch(void* const* d_in, const int* in_sizes, int n_in,
                              void* d_out, int out_size, void* d_ws, size_t ws_size,
                              hipStream_t stream) {
    const float* X  = (const float*)d_in[0];
    const float* W1 = (const float*)d_in[1];
    const float* W2 = (const float*)d_in[2];
    const float* W3 = (const float*)d_in[3];
    float* out = (float*)d_out;

    const int B = in_sizes[0] / 81;        // 524288
    const int nblocks = B / 64;            // 8192 one-wave blocks
    spd_encoder_kernel<<<nblocks, 64, 0, stream>>>(X, W1, W2, W3, out);
}